// Round 4
// baseline (11958.414 us; speedup 1.0000x reference)
//
#include <hip/hip_runtime.h>

using short8 = __attribute__((ext_vector_type(8))) short;
using sh4    = __attribute__((ext_vector_type(4))) short;
using f32x4  = __attribute__((ext_vector_type(4))) float;

#define DEVI static __device__ __forceinline__

DEVI unsigned short f2bf(float f) {
  union { float f; unsigned u; } v; v.f = f;
  unsigned r = v.u + 0x7FFFu + ((v.u >> 16) & 1u);
  return (unsigned short)(r >> 16);
}
DEVI float bf2f(unsigned short h) {
  union { unsigned u; float f; } v; v.u = (unsigned)h << 16;
  return v.f;
}
DEVI void splitf(float f, unsigned short& hi, unsigned short& lo) {
  unsigned short h = f2bf(f);
  hi = h;
  lo = f2bf(f - bf2f(h));
}

static constexpr int  B_  = 64;
static constexpr int  S_  = 512;
static constexpr int  IN_ = 512;
static constexpr int  NB_ = 64;    // n_blk
static constexpr int  DH_ = 1024;  // d_hid
static constexpr long M_  = (long)B_ * S_;  // 32768 rows

#define MFMA16(a, b, c) __builtin_amdgcn_mfma_f32_16x16x32_bf16(a, b, c, 0, 0, 0)

// ---------------------------------------------------------------------------
// prep: split-transpose all weights to bf16 hi/lo pairs [n][k]; init h buffer;
// zero the sync flags (folded in: no hipMemsetAsync needed in kernel_launch).
// ---------------------------------------------------------------------------
__global__ void prep_kernel(const float* __restrict__ Wmc, const float* __restrict__ Wig,
                            const float* __restrict__ Wog,
                            const float* __restrict__ Umc, const float* __restrict__ Uig,
                            const float* __restrict__ Uog,
                            const float* __restrict__ h0,
                            unsigned short* __restrict__ WmcTh, unsigned short* __restrict__ WmcTl,
                            unsigned short* __restrict__ WigTh, unsigned short* __restrict__ WigTl,
                            unsigned short* __restrict__ WogTh, unsigned short* __restrict__ WogTl,
                            unsigned short* __restrict__ UmcTh, unsigned short* __restrict__ UmcTl,
                            unsigned short* __restrict__ UigTh, unsigned short* __restrict__ UigTl,
                            unsigned short* __restrict__ UogTh, unsigned short* __restrict__ UogTl,
                            unsigned short* __restrict__ hbh,   unsigned short* __restrict__ hbl,
                            int* __restrict__ flags)
{
  const long e0 = 1024L * 512;        // WmcT
  const long e1 = e0 + 64L * 512;     // WigT
  const long e2 = e1 + 64L * 512;     // WogT
  const long e3 = e2 + 1024L * 1024;  // UmcT
  const long e4 = e3 + 64L * 1024;    // UigT
  const long e5 = e4 + 64L * 1024;    // UogT
  const long e6 = e5 + 64L * 1024;    // hbuf
  const long e7 = e6 + 512L * 32;     // flags
  for (long i = (long)blockIdx.x * blockDim.x + threadIdx.x; i < e7;
       i += (long)gridDim.x * blockDim.x) {
    if (i >= e6) { flags[i - e6] = 0; continue; }
    float v; unsigned short *ph, *pl; long idx;
    if (i < e0) {
      idx = i; long n = idx >> 9, k = idx & 511;
      v = Wmc[k * 1024 + n]; ph = WmcTh; pl = WmcTl;
    } else if (i < e1) {
      idx = i - e0; long n = idx >> 9, k = idx & 511;
      v = Wig[k * 64 + n]; ph = WigTh; pl = WigTl;
    } else if (i < e2) {
      idx = i - e1; long n = idx >> 9, k = idx & 511;
      v = Wog[k * 64 + n]; ph = WogTh; pl = WogTl;
    } else if (i < e3) {
      idx = i - e2; long n = idx >> 10, k = idx & 1023;
      v = Umc[k * 1024 + n]; ph = UmcTh; pl = UmcTl;
    } else if (i < e4) {
      idx = i - e3; long n = idx >> 10, k = idx & 1023;
      v = Uig[k * 64 + n]; ph = UigTh; pl = UigTl;
    } else if (i < e5) {
      idx = i - e4; long n = idx >> 10, k = idx & 1023;
      v = Uog[k * 64 + n]; ph = UogTh; pl = UogTl;
    } else {
      idx = i - e5;
      v = h0[idx & 1023]; ph = hbh; pl = hbl;
    }
    unsigned short hi, lo; splitf(v, hi, lo);
    ph[idx] = hi; pl[idx] = lo;
  }
}

// ---------------------------------------------------------------------------
// Split-precision GEMM: C(MxN f32) = A(MxK f32) @ BT(NxK bf16 hi/lo)^T + bias.
// K=512. Block tile 128x64, BK=64, 4 waves 2x2 (wave tile 64x32).
// ---------------------------------------------------------------------------
__global__ __launch_bounds__(256) void gemm_split(
    const float* __restrict__ A,
    const unsigned short* __restrict__ BTh,
    const unsigned short* __restrict__ BTl,
    const float* __restrict__ bias,
    float* __restrict__ C,
    int N)
{
  const int K = 512;
  __shared__ unsigned short Ah[128][72];
  __shared__ unsigned short Alo[128][72];
  __shared__ unsigned short Bh[64][72];
  __shared__ unsigned short Blo[64][72];
  int tid = threadIdx.x, lane = tid & 63, w = tid >> 6;
  int wm = w & 1, wn = w >> 1;
  int m0 = blockIdx.x * 128, n0 = blockIdx.y * 64;
  f32x4 acc[4][2] = {};
  for (int kt = 0; kt < K; kt += 64) {
    __syncthreads();
#pragma unroll
    for (int i = 0; i < 8; ++i) {  // A tile: 128 rows x 64 cols (f32 -> split)
      int c = tid + i * 256; int r = c >> 4, o = (c & 15) * 4;
      float4 v = *(const float4*)&A[(long)(m0 + r) * K + kt + o];
      sh4 hi, lo;
      { unsigned short h_, l_;
        splitf(v.x, h_, l_); hi[0] = (short)h_; lo[0] = (short)l_;
        splitf(v.y, h_, l_); hi[1] = (short)h_; lo[1] = (short)l_;
        splitf(v.z, h_, l_); hi[2] = (short)h_; lo[2] = (short)l_;
        splitf(v.w, h_, l_); hi[3] = (short)h_; lo[3] = (short)l_; }
      *(sh4*)&Ah[r][o]  = hi;
      *(sh4*)&Alo[r][o] = lo;
    }
#pragma unroll
    for (int i = 0; i < 2; ++i) {  // B tiles: 64 n-rows x 64 k-cols
      int c = tid + i * 256; int r = c >> 3, o = (c & 7) * 8;
      *(short8*)&Bh[r][o]  = *(const short8*)&BTh[(long)(n0 + r) * K + kt + o];
      *(short8*)&Blo[r][o] = *(const short8*)&BTl[(long)(n0 + r) * K + kt + o];
    }
    __syncthreads();
#pragma unroll
    for (int ks = 0; ks < 2; ++ks) {
      short8 ah[4], al[4], bh[2], bl[2];
      int kk = ks * 32 + (lane >> 4) * 8;
#pragma unroll
      for (int mt = 0; mt < 4; ++mt) {
        ah[mt] = *(const short8*)&Ah[wm * 64 + mt * 16 + (lane & 15)][kk];
        al[mt] = *(const short8*)&Alo[wm * 64 + mt * 16 + (lane & 15)][kk];
      }
#pragma unroll
      for (int nt = 0; nt < 2; ++nt) {
        bh[nt] = *(const short8*)&Bh[wn * 32 + nt * 16 + (lane & 15)][kk];
        bl[nt] = *(const short8*)&Blo[wn * 32 + nt * 16 + (lane & 15)][kk];
      }
#pragma unroll
      for (int mt = 0; mt < 4; ++mt)
#pragma unroll
        for (int nt = 0; nt < 2; ++nt) {
          acc[mt][nt] = MFMA16(ah[mt], bl[nt], acc[mt][nt]);
          acc[mt][nt] = MFMA16(al[mt], bh[nt], acc[mt][nt]);
          acc[mt][nt] = MFMA16(ah[mt], bh[nt], acc[mt][nt]);
        }
    }
  }
#pragma unroll
  for (int mt = 0; mt < 4; ++mt)
#pragma unroll
    for (int nt = 0; nt < 2; ++nt) {
      int col = n0 + wn * 32 + nt * 16 + (lane & 15);
      float bv = bias[col];
#pragma unroll
      for (int r = 0; r < 4; ++r) {
        int row = m0 + wm * 64 + mt * 16 + (lane >> 4) * 4 + r;
        C[(long)row * N + col] = acc[mt][nt][r] + bv;
      }
    }
}

// ---------------------------------------------------------------------------
// Persistent scan: 32 blocks x 256 threads run all 512 steps.
// Block n owns Umc cols [32n,32n+32) + gate blks {2n,2n+1}; all 64 batch rows.
// Waves split K=1024 into 4x256; LDS reduce. Weights + c stay in registers.
// Cross-block sync: per-step per-block flags (release store / relaxed poll +
// threadfence acquire), h double-buffered as bf16 hi/lo. Spin is BOUNDED so a
// protocol failure shows up as absmax error, not a dead container.
// ---------------------------------------------------------------------------
__global__ __launch_bounds__(256, 1) void lstm_scan(
    unsigned short* __restrict__ hAh, unsigned short* __restrict__ hAl,
    unsigned short* __restrict__ hBh, unsigned short* __restrict__ hBl,
    const unsigned short* __restrict__ UmcTh, const unsigned short* __restrict__ UmcTl,
    const unsigned short* __restrict__ UigTh, const unsigned short* __restrict__ UigTl,
    const unsigned short* __restrict__ UogTh, const unsigned short* __restrict__ UogTl,
    const float* __restrict__ xig, const float* __restrict__ xog,
    const float* __restrict__ c0,
    float* __restrict__ hseq, float* __restrict__ cseq,
    int* __restrict__ flags)
{
  __shared__ float pA[4][64][33];
  __shared__ float pG[4][64][17];
  const int tid = threadIdx.x, lane = tid & 63, w = tid >> 6;
  const int n = blockIdx.x;  // 0..31

  // ---- preload weight fragments into registers (per-wave K slice) ----
  short8 b0h[2][8], b0l[2][8], b1h[8], b1l[8];
  {
    int c = lane & 15;
    int s = c & 1, dl = (c >> 1) & 1;
    const unsigned short *gh, *gl;
    if (c < 4) {  // gate tile cols: 0=ig(2n) 1=og(2n) 2=ig(2n+1) 3=og(2n+1)
      gh = (s ? UogTh : UigTh) + (long)(2 * n + dl) * DH_;
      gl = (s ? UogTl : UigTl) + (long)(2 * n + dl) * DH_;
    } else {      // junk lanes: duplicate ig(2n)
      gh = UigTh + (long)(2 * n) * DH_;
      gl = UigTl + (long)(2 * n) * DH_;
    }
#pragma unroll
    for (int k8 = 0; k8 < 8; ++k8) {
      int kk = w * 256 + k8 * 32 + (lane >> 4) * 8;
#pragma unroll
      for (int nt = 0; nt < 2; ++nt) {
        long br = (long)(32 * n + 16 * nt + c) * DH_ + kk;
        b0h[nt][k8] = *(const short8*)&UmcTh[br];
        b0l[nt][k8] = *(const short8*)&UmcTl[br];
      }
      b1h[k8] = *(const short8*)&gh[kk];
      b1l[k8] = *(const short8*)&gl[kk];
    }
  }
  // ---- c state in registers: thread owns column (32n + tid&31), rows (tid>>5)+8e
  float c_reg[8];
  {
    float cv = c0[32 * n + (tid & 31)];
#pragma unroll
    for (int e = 0; e < 8; ++e) c_reg[e] = cv;
  }

  for (int t = 0; t < S_; ++t) {
    unsigned short *hh, *hl, *oh, *ol;
    if (t & 1) { hh = hBh; hl = hBl; oh = hAh; ol = hAl; }
    else       { hh = hAh; hl = hAl; oh = hBh; ol = hBl; }

    if (t) {  // wait for all 32 producers of h_t (bounded spin: see header)
      if (lane < 32) {
        const int* f = flags + (t - 1) * 32;
        long guard = 0;
        while (__hip_atomic_load(&f[lane], __ATOMIC_RELAXED,
                                 __HIP_MEMORY_SCOPE_AGENT) == 0 &&
               guard < 20000000L) {
          __builtin_amdgcn_s_sleep(2);
          ++guard;
        }
      }
      __threadfence();  // acquire: make producers' h writes visible
    }

    f32x4 acc0[2][4] = {};
    f32x4 acc1[4] = {};
#pragma unroll
    for (int k8 = 0; k8 < 8; ++k8) {
      int kk = w * 256 + k8 * 32 + (lane >> 4) * 8;
      short8 ah[4], al[4];
#pragma unroll
      for (int mt = 0; mt < 4; ++mt) {
        long ar = (long)(mt * 16 + (lane & 15)) * DH_ + kk;
        ah[mt] = *(const short8*)&hh[ar];
        al[mt] = *(const short8*)&hl[ar];
      }
#pragma unroll
      for (int mt = 0; mt < 4; ++mt) {
#pragma unroll
        for (int nt = 0; nt < 2; ++nt) {
          acc0[nt][mt] = MFMA16(ah[mt], b0l[nt][k8], acc0[nt][mt]);
          acc0[nt][mt] = MFMA16(al[mt], b0h[nt][k8], acc0[nt][mt]);
          acc0[nt][mt] = MFMA16(ah[mt], b0h[nt][k8], acc0[nt][mt]);
        }
        acc1[mt] = MFMA16(ah[mt], b1l[k8], acc1[mt]);
        acc1[mt] = MFMA16(al[mt], b1h[k8], acc1[mt]);
        acc1[mt] = MFMA16(ah[mt], b1h[k8], acc1[mt]);
      }
    }
#pragma unroll
    for (int mt = 0; mt < 4; ++mt) {
#pragma unroll
      for (int r = 0; r < 4; ++r) {
        int row = mt * 16 + (lane >> 4) * 4 + r;
#pragma unroll
        for (int nt = 0; nt < 2; ++nt)
          pA[w][row][nt * 16 + (lane & 15)] = acc0[nt][mt][r];
        pG[w][row][lane & 15] = acc1[mt][r];
      }
    }
    __syncthreads();
#pragma unroll
    for (int e = 0; e < 8; ++e) {
      int idx = tid + e * 256;      // 0..2047
      int bi = idx >> 5, jl = idx & 31, bl = jl >> 4;
      float gsum = pA[0][bi][jl] + pA[1][bi][jl] + pA[2][bi][jl] + pA[3][bi][jl];
      float isum = pG[0][bi][2*bl]   + pG[1][bi][2*bl]   + pG[2][bi][2*bl]   + pG[3][bi][2*bl];
      float osum = pG[0][bi][2*bl+1] + pG[1][bi][2*bl+1] + pG[2][bi][2*bl+1] + pG[3][bi][2*bl+1];
      int j = 32 * n + jl;
      long base = ((long)bi * S_ + t) * DH_ + j;
      long xb   = ((long)bi * S_ + t) * NB_ + 2 * n + bl;
      float gpre = hseq[base] + gsum;   // xmc staged in hseq
      float ipre = xig[xb] + isum;
      float opre = xog[xb] + osum;
      float ig = 1.f / (1.f + __expf(-ipre));
      float og = 1.f / (1.f + __expf(-opre));
      float g  = tanhf(gpre);
      float cn = c_reg[e] + ig * g;
      float hv = og * tanhf(cn);
      c_reg[e] = cn;
      cseq[base] = cn;
      hseq[base] = hv;                  // overwrite xmc slot
      unsigned short hhv, hlv; splitf(hv, hhv, hlv);
      long ho = (long)bi * DH_ + j;
      oh[ho] = hhv; ol[ho] = hlv;
    }
    __threadfence();   // release: flush h writes toward coherence point
    __syncthreads();   // all threads' writes + fences done
    if (tid == 0)
      __hip_atomic_store(&flags[t * 32 + n], 1, __ATOMIC_RELEASE,
                         __HIP_MEMORY_SCOPE_AGENT);
  }
}

// ---------------------------------------------------------------------------
extern "C" void kernel_launch(void* const* d_in, const int* in_sizes, int n_in,
                              void* d_out, int out_size, void* d_ws, size_t ws_size,
                              hipStream_t stream) {
  const float* x   = (const float*)d_in[0];
  const float* h0  = (const float*)d_in[1];
  const float* c0  = (const float*)d_in[2];
  const float* Wig = (const float*)d_in[3];
  const float* Uig = (const float*)d_in[4];
  const float* big = (const float*)d_in[5];
  const float* Wog = (const float*)d_in[6];
  const float* Uog = (const float*)d_in[7];
  const float* bog = (const float*)d_in[8];
  const float* Wmc = (const float*)d_in[9];
  const float* Umc = (const float*)d_in[10];
  const float* bmc = (const float*)d_in[11];

  char* ws = (char*)d_ws;
  size_t off = 0;
  auto alloc = [&](size_t bytes) { void* p = ws + off; off += (bytes + 255) & ~255UL; return p; };
  unsigned short* WmcTh = (unsigned short*)alloc(1024L * 512 * 2);
  unsigned short* WmcTl = (unsigned short*)alloc(1024L * 512 * 2);
  unsigned short* WigTh = (unsigned short*)alloc(64L * 512 * 2);
  unsigned short* WigTl = (unsigned short*)alloc(64L * 512 * 2);
  unsigned short* WogTh = (unsigned short*)alloc(64L * 512 * 2);
  unsigned short* WogTl = (unsigned short*)alloc(64L * 512 * 2);
  unsigned short* UmcTh = (unsigned short*)alloc(1024L * 1024 * 2);
  unsigned short* UmcTl = (unsigned short*)alloc(1024L * 1024 * 2);
  unsigned short* UigTh = (unsigned short*)alloc(64L * 1024 * 2);
  unsigned short* UigTl = (unsigned short*)alloc(64L * 1024 * 2);
  unsigned short* UogTh = (unsigned short*)alloc(64L * 1024 * 2);
  unsigned short* UogTl = (unsigned short*)alloc(64L * 1024 * 2);
  unsigned short* hAh   = (unsigned short*)alloc(64L * 1024 * 2);
  unsigned short* hAl   = (unsigned short*)alloc(64L * 1024 * 2);
  unsigned short* hBh   = (unsigned short*)alloc(64L * 1024 * 2);
  unsigned short* hBl   = (unsigned short*)alloc(64L * 1024 * 2);
  float* xig            = (float*)alloc(M_ * 64 * 4);
  float* xog            = (float*)alloc(M_ * 64 * 4);
  int*   flags          = (int*)alloc(512L * 32 * 4);

  float* hseq = (float*)d_out;
  float* cseq = hseq + M_ * DH_;

  prep_kernel<<<2048, 256, 0, stream>>>(Wmc, Wig, Wog, Umc, Uig, Uog, h0,
                                        WmcTh, WmcTl, WigTh, WigTl, WogTh, WogTl,
                                        UmcTh, UmcTl, UigTh, UigTl, UogTh, UogTl,
                                        hAh, hAl, flags);
  // Input projections (split precision); xmc goes straight into hseq.
  gemm_split<<<dim3(256, 16), 256, 0, stream>>>(x, WmcTh, WmcTl, bmc, hseq, 1024);
  gemm_split<<<dim3(256, 1), 256, 0, stream>>>(x, WigTh, WigTl, big, xig, 64);
  gemm_split<<<dim3(256, 1), 256, 0, stream>>>(x, WogTh, WogTl, bog, xog, 64);

  lstm_scan<<<32, 256, 0, stream>>>(hAh, hAl, hBh, hBl,
                                    UmcTh, UmcTl, UigTh, UigTl, UogTh, UogTl,
                                    xig, xog, c0, hseq, cseq, flags);
}